// Round 18
// baseline (154.846 us; speedup 1.0000x reference)
//
#include <hip/hip_runtime.h>
#include <hip/hip_fp16.h>
#include <math.h>

// Problem constants (from reference)
#define NN 20000          // nodes
#define TT 4              // time steps
#define EE 320000         // edges
#define NT (NN*TT)        // 80000 rows
#define H1 8              // heads layer 1
#define C1 128            // heads*f_out layer 1
#define IN_F 32
#define OUT_F 16
#define CAP 96            // bucket capacity; max degree Poisson(16) << 96
#define SCAT_BLOCKS 313   // ceil((EE/4)/256)
#define XCAST_BLOCKS 1250 // NT/64

typedef _Float16 h8 __attribute__((ext_vector_type(8)));
typedef float f32x4 __attribute__((ext_vector_type(4)));

__device__ __forceinline__ float lrelu_exp(float e) {
  e = (e >= 0.f) ? e : 0.2f * e;
  return __expf(e);
}

// ---------------------------------------------------------------------------
// K0 "prep" (replaces the cnt memset — same dispatch count): blocks 0..78
// zero cnt; block 79 builds ALL weight fragments globally ONCE (ELERg for
// k_front's el/er MFMA, W1hp per-head B-frags, W2pp). R10/R17 lesson: never
// rebuild weight tiles per consumer block.
// ---------------------------------------------------------------------------
__global__ __launch_bounds__(256) void k_prep(
    const float* __restrict__ W1, const float* __restrict__ al1,
    const float* __restrict__ ar1, const float* __restrict__ W2,
    const float* __restrict__ al2, const float* __restrict__ ar2,
    int* __restrict__ cnt, __half* __restrict__ ELERg,
    __half* __restrict__ W1hp, __half* __restrict__ W2pp) {
  int b = blockIdx.x;
  int tid = threadIdx.x;
  if (b < 79) {
    int i = b * 256 + tid;
    if (i < NN) cnt[i] = 0;
    return;
  }
  // ---- weight prep (single block) ----
  // ELERg: one B-frag tile [Wl|Wr] per-head dots
  for (int idx = tid; idx < 512; idx += 256) {
    int lane = idx >> 3, j = idx & 7;
    int k = (lane >> 4) * 8 + j;
    int n = lane & 15;
    int hh_ = n & 7;
    const float* a = (n < 8) ? al1 : ar1;
    float s = 0.f;
    for (int f = 0; f < 16; ++f) s += W1[k * C1 + hh_ * 16 + f] * a[hh_ * 16 + f];
    ELERg[idx] = __float2half(s);
  }
  // W1hp: 8 per-head B-frag tiles, B[k][n] with n=lane&15, k=(lane>>4)*8+j
  for (int idx = tid; idx < 8 * 512; idx += 256) {
    int tile = idx >> 9;
    int rem = idx & 511;
    int lane = rem >> 3, j = rem & 7;
    int k = (lane >> 4) * 8 + j;
    int n = lane & 15;
    W1hp[idx] = __float2half(W1[k * C1 + tile * 16 + n]);
  }
  // W2pp: 4 feat k-step tiles + 4 [Wl2|Wr2|0] k-step tiles
  for (int idx = tid; idx < 8 * 512; idx += 256) {
    int tile = idx >> 9;
    int rem = idx & 511;
    int lane = rem >> 3, j = rem & 7;
    int ks = tile & 3;
    int k = ks * 32 + (lane >> 4) * 8 + j;
    int n = lane & 15;
    float v = 0.f;
    if (tile < 4) {
      v = W2[k * OUT_F + n];
    } else if (n == 0) {
      float s = 0.f;
      for (int f = 0; f < 16; ++f) s += W2[k * OUT_F + f] * al2[f];
      v = s;
    } else if (n == 1) {
      float s = 0.f;
      for (int f = 0; f < 16; ++f) s += W2[k * OUT_F + f] * ar2[f];
      v = s;
    }
    W2pp[idx] = __float2half(v);
  }
}

// ---------------------------------------------------------------------------
// K1 "front": blocks 0..312 = bucket-CSR scatter; blocks 313.. = x cast to
// fp16 + el1/er1 via one ELER MFMA. ELER fragment loaded straight from
// global (built once by k_prep; L2-resident) — no LDS build, no barrier.
// ---------------------------------------------------------------------------
__global__ __launch_bounds__(256) void k_front(
    const float* __restrict__ x,
    const int4* __restrict__ src4, const int4* __restrict__ dst4,
    int* __restrict__ cnt, int* __restrict__ csr96,
    const __half* __restrict__ ELERg,
    __half* __restrict__ xh, float* __restrict__ el1, float* __restrict__ er1) {
  int b = blockIdx.x;
  int tid = threadIdx.x;
  if (b < SCAT_BLOCKS) {
    int e4 = b * 256 + tid;
    if (e4 < EE / 4) {
      int4 s = src4[e4];
      int4 d = dst4[e4];
      int p0 = atomicAdd(&cnt[d.x], 1); csr96[d.x * CAP + p0] = s.x;
      int p1 = atomicAdd(&cnt[d.y], 1); csr96[d.y * CAP + p1] = s.y;
      int p2 = atomicAdd(&cnt[d.z], 1); csr96[d.z * CAP + p2] = s.z;
      int p3 = atomicAdd(&cnt[d.w], 1); csr96[d.w * CAP + p3] = s.w;
    }
    return;
  }
  // ---- xcast + el/er branch ----
  int wave = tid >> 6, lane = tid & 63;
  int m = lane & 15, quad = lane >> 4;
  int rowbase = (b - SCAT_BLOCKS) * 64 + wave * 16;
  int row = rowbase + m;
  const float4* xp = (const float4*)(x + row * IN_F + quad * 8);
  float4 a0 = xp[0], a1 = xp[1];
  h8 af;
  af[0] = (_Float16)a0.x; af[1] = (_Float16)a0.y;
  af[2] = (_Float16)a0.z; af[3] = (_Float16)a0.w;
  af[4] = (_Float16)a1.x; af[5] = (_Float16)a1.y;
  af[6] = (_Float16)a1.z; af[7] = (_Float16)a1.w;
  *(h8*)(xh + (size_t)row * IN_F + quad * 8) = af;   // fp16 x copy
  {
    h8 bf = ((const h8*)ELERg)[lane];
    f32x4 c = {0.f, 0.f, 0.f, 0.f};
    c = __builtin_amdgcn_mfma_f32_16x16x32_f16(af, bf, c, 0, 0, 0);
#pragma unroll
    for (int r = 0; r < 4; ++r) {
      int orow = rowbase + quad * 4 + r;
      if (m < 8) el1[orow * H1 + m] = c[r];
      else       er1[orow * H1 + (m - 8)] = c[r];
    }
  }
}

// ---------------------------------------------------------------------------
// K2: layer-1 x-form aggregate (R16's winning pk_fma hot loop, UNCHANGED)
// + FUSED mid GEMMs in a barrier-fenced epilogue. Each block's 4 waves hold
// exactly one 16-row M-tile (4 nodes x 4 t): normalized aggx tile -> padded
// LDS; phase 1 (per-head GEMM, 2 heads/wave); phase 2 (feat2/el2/er2 GEMM,
// wave 0). No aggx global round-trip.
// ---------------------------------------------------------------------------
__global__ __launch_bounds__(256) void k_agg1m(
    const __half* __restrict__ xh,       // [nt][32]
    const float* __restrict__ el1,       // [n][32] = [n][t][8]
    const float* __restrict__ er1,
    const int* __restrict__ cnt, const int* __restrict__ csr96,
    const __half* __restrict__ W1hp, const float* __restrict__ b1,
    const __half* __restrict__ W2pp,
    __half* __restrict__ feat2h, float* __restrict__ el2,
    float* __restrict__ er2) {
  __shared__ __half axs[16][264];        // 8.4 KB aggx tile, stride-264 pad
  __shared__ __half hs[16][136];         // 4.3 KB h tile, stride-136 pad
  int tid = threadIdx.x;
  int wv = tid >> 6, lane = tid & 63;
  int n = blockIdx.x * 4 + wv;
  int slot = lane >> 1;                  // (t,h): t=slot>>3, h=slot&7
  int t = lane >> 4;                     // == slot>>3
  int hf = lane & 1;
  float er_i = er1[(size_t)n * 32 + slot];
  int deg = cnt[n];
  const int* eb = csr96 + (size_t)n * CAP;
  h8 accA = {0, 0, 0, 0, 0, 0, 0, 0};
  h8 accB = {0, 0, 0, 0, 0, 0, 0, 0};
  float l = 0.f;
  for (int chunk = 0; chunk < deg; chunk += 64) {
    int m = min(64, deg - chunk);
    int sv = (lane < m) ? eb[chunk + lane] : 0;
    int iters = (m + 3) >> 2;
    for (int g = 0; g < iters; ++g) {
      int j = g * 4;
      int s0 = __builtin_amdgcn_readlane(sv, j + 0);
      int s1 = __builtin_amdgcn_readlane(sv, j + 1);
      int s2 = __builtin_amdgcn_readlane(sv, j + 2);
      int s3 = __builtin_amdgcn_readlane(sv, j + 3);
      float ew0 = el1[(size_t)s0 * 32 + slot];
      float ew1 = el1[(size_t)s1 * 32 + slot];
      float ew2 = el1[(size_t)s2 * 32 + slot];
      float ew3 = el1[(size_t)s3 * 32 + slot];
      const __half* x0 = xh + (size_t)(s0 * 4 + t) * 32 + hf * 16;
      const __half* x1 = xh + (size_t)(s1 * 4 + t) * 32 + hf * 16;
      const __half* x2 = xh + (size_t)(s2 * 4 + t) * 32 + hf * 16;
      const __half* x3 = xh + (size_t)(s3 * 4 + t) * 32 + hf * 16;
      h8 a0 = *(const h8*)x0, b0 = *(const h8*)(x0 + 8);
      h8 a1 = *(const h8*)x1, b1_ = *(const h8*)(x1 + 8);
      h8 a2 = *(const h8*)x2, b2_ = *(const h8*)(x2 + 8);
      h8 a3 = *(const h8*)x3, b3_ = *(const h8*)(x3 + 8);
#define CONSUME(K, EW, XA, XB)                                    \
      {                                                           \
        float w_ = lrelu_exp(EW + er_i);                          \
        w_ = (j + K < m) ? w_ : 0.f;                              \
        l += w_;                                                  \
        _Float16 wh_ = (_Float16)w_;                              \
        h8 w8_ = {wh_, wh_, wh_, wh_, wh_, wh_, wh_, wh_};        \
        accA += w8_ * XA;                                         \
        accB += w8_ * XB;                                         \
      }
      CONSUME(0, ew0, a0, b0) CONSUME(1, ew1, a1, b1_)
      CONSUME(2, ew2, a2, b2_) CONSUME(3, ew3, a3, b3_)
#undef CONSUME
    }
  }
  float inv = (l > 0.f) ? (1.f / l) : 0.f;
  {
    h8 r0, r1;
#pragma unroll
    for (int q = 0; q < 8; ++q) {
      r0[q] = (_Float16)((float)accA[q] * inv);
      r1[q] = (_Float16)((float)accB[q] * inv);
    }
    int hh_ = slot & 7;
    __half* op = &axs[wv * 4 + t][hh_ * 32 + hf * 16];
    *(h8*)op = r0;
    *(h8*)(op + 8) = r1;
  }
  __syncthreads();

  // ---- fused mid epilogue (barrier-fenced, cold code) ----
  int m = lane & 15, quad = lane >> 4;
  const h8* bp1 = (const h8*)W1hp;
  // phase 1: wave wv computes heads 2wv, 2wv+1 -> hs
#pragma unroll
  for (int hi = 0; hi < 2; ++hi) {
    int head = wv * 2 + hi;
    h8 af = *(const h8*)&axs[m][head * 32 + quad * 8];
    f32x4 c = {0.f, 0.f, 0.f, 0.f};
    c = __builtin_amdgcn_mfma_f32_16x16x32_f16(af, bp1[head * 64 + lane], c, 0, 0, 0);
    float bv = b1[head * 16 + m];
#pragma unroll
    for (int r = 0; r < 4; ++r)
      hs[quad * 4 + r][head * 16 + m] = __float2half(c[r] + bv);
  }
  __syncthreads();
  if (wv != 0) return;
  // phase 2: wave 0 computes feat2 + el2/er2 for the 16-row tile
  const h8* bp2 = (const h8*)W2pp;
  f32x4 cF = {0.f, 0.f, 0.f, 0.f};
  f32x4 cE = {0.f, 0.f, 0.f, 0.f};
#pragma unroll
  for (int ks = 0; ks < 4; ++ks) {
    h8 af = *(const h8*)&hs[m][ks * 32 + quad * 8];
    cF = __builtin_amdgcn_mfma_f32_16x16x32_f16(af, bp2[ks * 64 + lane], cF, 0, 0, 0);
    cE = __builtin_amdgcn_mfma_f32_16x16x32_f16(af, bp2[(4 + ks) * 64 + lane], cE, 0, 0, 0);
  }
#pragma unroll
  for (int r = 0; r < 4; ++r) {
    int orow = blockIdx.x * 16 + quad * 4 + r;
    feat2h[(size_t)orow * OUT_F + m] = __float2half(cF[r]);
    if (m == 0) el2[orow] = cE[r];
    if (m == 1) er2[orow] = cE[r];
  }
}

// ---------------------------------------------------------------------------
// K3: layer-2 aggregate, no-routing form. One wave per node; lane owns
// (t = lane>>4, f = lane&15); alpha computed locally; 8-edge batches.
// ---------------------------------------------------------------------------
__global__ __launch_bounds__(256) void k_agg2x(
    const __half* __restrict__ feat2h,   // [nt][16]
    const float* __restrict__ el2, const float* __restrict__ er2,  // [nt]
    const int* __restrict__ cnt, const int* __restrict__ csr96,
    const float* __restrict__ b2, float* __restrict__ out) {
  int tid = threadIdx.x;
  int wv = tid >> 6, lane = tid & 63;
  int n = blockIdx.x * 4 + wv;
  int t = lane >> 4, f = lane & 15;
  float ern = er2[n * 4 + t];
  int deg = cnt[n];
  const int* eb = csr96 + (size_t)n * CAP;
  float acc = 0.f, l = 0.f;
  for (int chunk = 0; chunk < deg; chunk += 64) {
    int m = min(64, deg - chunk);
    int sv = (lane < m) ? eb[chunk + lane] : 0;
    int iters = (m + 7) >> 3;
    for (int g = 0; g < iters; ++g) {
      int j = g * 8;
      int s0 = __builtin_amdgcn_readlane(sv, j + 0);
      int s1 = __builtin_amdgcn_readlane(sv, j + 1);
      int s2 = __builtin_amdgcn_readlane(sv, j + 2);
      int s3 = __builtin_amdgcn_readlane(sv, j + 3);
      int s4 = __builtin_amdgcn_readlane(sv, j + 4);
      int s5 = __builtin_amdgcn_readlane(sv, j + 5);
      int s6 = __builtin_amdgcn_readlane(sv, j + 6);
      int s7 = __builtin_amdgcn_readlane(sv, j + 7);
      float e0 = el2[s0 * 4 + t];
      float e1 = el2[s1 * 4 + t];
      float e2 = el2[s2 * 4 + t];
      float e3 = el2[s3 * 4 + t];
      float e4 = el2[s4 * 4 + t];
      float e5 = el2[s5 * 4 + t];
      float e6 = el2[s6 * 4 + t];
      float e7 = el2[s7 * 4 + t];
      __half f0 = feat2h[(size_t)(s0 * 4 + t) * OUT_F + f];
      __half f1 = feat2h[(size_t)(s1 * 4 + t) * OUT_F + f];
      __half f2 = feat2h[(size_t)(s2 * 4 + t) * OUT_F + f];
      __half f3 = feat2h[(size_t)(s3 * 4 + t) * OUT_F + f];
      __half f4 = feat2h[(size_t)(s4 * 4 + t) * OUT_F + f];
      __half f5 = feat2h[(size_t)(s5 * 4 + t) * OUT_F + f];
      __half f6 = feat2h[(size_t)(s6 * 4 + t) * OUT_F + f];
      __half f7 = feat2h[(size_t)(s7 * 4 + t) * OUT_F + f];
#define CONSUME(K, EW, FV)                                        \
      {                                                           \
        float w_ = lrelu_exp(EW + ern);                           \
        w_ = (j + K < m) ? w_ : 0.f;                              \
        l += w_;                                                  \
        acc = fmaf(w_, __half2float(FV), acc);                    \
      }
      CONSUME(0, e0, f0) CONSUME(1, e1, f1)
      CONSUME(2, e2, f2) CONSUME(3, e3, f3)
      CONSUME(4, e4, f4) CONSUME(5, e5, f5)
      CONSUME(6, e6, f6) CONSUME(7, e7, f7)
#undef CONSUME
    }
  }
  float inv = (l > 0.f) ? (1.f / l) : 0.f;
  out[(size_t)(n * 4 + t) * OUT_F + f] = acc * inv + b2[f];
}

// ---------------------------------------------------------------------------
extern "C" void kernel_launch(void* const* d_in, const int* in_sizes, int n_in,
                              void* d_out, int out_size, void* d_ws, size_t ws_size,
                              hipStream_t stream) {
  const float* x   = (const float*)d_in[0];
  const int*   src = (const int*)d_in[1];
  const int*   dst = (const int*)d_in[2];
  const float* W1  = (const float*)d_in[3];
  const float* al1 = (const float*)d_in[4];
  const float* ar1 = (const float*)d_in[5];
  const float* b1  = (const float*)d_in[6];
  const float* W2  = (const float*)d_in[7];
  const float* al2 = (const float*)d_in[8];
  const float* ar2 = (const float*)d_in[9];
  const float* b2  = (const float*)d_in[10];
  float* out = (float*)d_out;

  // Workspace layout (bytes, 256-aligned chunks), ~22 MB total
  char* w = (char*)d_ws;
  __half* xh     = (__half*)w; w += (size_t)NT * IN_F * 2;      // 5.12 MB
  __half* feat2h = (__half*)w; w += (size_t)NT * OUT_F * 2;     // 2.56 MB
  float*  el1    = (float*)w;  w += (size_t)NT * H1 * 4;        // 2.56 MB
  float*  er1    = (float*)w;  w += (size_t)NT * H1 * 4;
  float*  el2    = (float*)w;  w += (size_t)NT * 4;             // 0.32 MB
  float*  er2    = (float*)w;  w += (size_t)NT * 4;
  __half* ELERg  = (__half*)w; w += (size_t)512 * 2;
  __half* W1hp   = (__half*)w; w += (size_t)8 * 512 * 2;
  __half* W2pp   = (__half*)w; w += (size_t)8 * 512 * 2;
  int* cnt     = (int*)w;      w += (size_t)NN * 4;             // 80 KB
  int* csr96   = (int*)w;      w += (size_t)NN * CAP * 4;       // 7.68 MB

  k_prep<<<80, 256, 0, stream>>>(W1, al1, ar1, W2, al2, ar2,
                                 cnt, ELERg, W1hp, W2pp);
  k_front<<<SCAT_BLOCKS + XCAST_BLOCKS, 256, 0, stream>>>(
      x, (const int4*)src, (const int4*)dst, cnt, csr96, ELERg,
      xh, el1, er1);
  k_agg1m<<<NN / 4, 256, 0, stream>>>(xh, el1, er1, cnt, csr96,
                                      W1hp, b1, W2pp, feat2h, el2, er2);
  k_agg2x<<<NN / 4, 256, 0, stream>>>(feat2h, el2, er2, cnt, csr96, b2, out);
}

// Round 19
// 149.784 us; speedup vs baseline: 1.0338x; 1.0338x over previous
//
#include <hip/hip_runtime.h>
#include <hip/hip_fp16.h>
#include <math.h>

// Problem constants (from reference)
#define NN 20000          // nodes
#define TT 4              // time steps
#define EE 320000         // edges
#define NT (NN*TT)        // 80000 rows
#define H1 8              // heads layer 1
#define C1 128            // heads*f_out layer 1
#define IN_F 32
#define OUT_F 16
#define CAP 96            // bucket capacity; max degree Poisson(16) << 96
#define SCAT_BLOCKS 313   // ceil((EE/4)/256)
#define XCAST_BLOCKS 1250 // NT/64

typedef _Float16 h8 __attribute__((ext_vector_type(8)));
typedef float f32x4 __attribute__((ext_vector_type(4)));

__device__ __forceinline__ float lrelu_exp(float e) {
  e = (e >= 0.f) ? e : 0.2f * e;
  return __expf(e);
}

// ---------------------------------------------------------------------------
// K1 "front": blocks 0..312 = bucket-CSR scatter; block 313 = global weight
// prep (W1hp per-head B-frags + W2pp); blocks 314.. = x cast to fp16 +
// el1/er1 via one ELER MFMA (ELER tile built in LDS: 1 tile, cheap).
// R18 note: splitting prep into its own kernel was neutral-negative — this
// merged layout is the measured optimum (152.9 µs total).
// ---------------------------------------------------------------------------
__global__ __launch_bounds__(256) void k_front(
    const float* __restrict__ x, const float* __restrict__ W1,
    const float* __restrict__ al1, const float* __restrict__ ar1,
    const float* __restrict__ W2, const float* __restrict__ al2,
    const float* __restrict__ ar2,
    const int4* __restrict__ src4, const int4* __restrict__ dst4,
    int* __restrict__ cnt, int* __restrict__ csr96,
    __half* __restrict__ xh, float* __restrict__ el1, float* __restrict__ er1,
    __half* __restrict__ W1hp, __half* __restrict__ W2pp) {
  __shared__ h8 ELERs[64];               // 1 KB, xcast branch only
  int b = blockIdx.x;
  int tid = threadIdx.x;
  if (b < SCAT_BLOCKS) {
    int e4 = b * 256 + tid;
    if (e4 < EE / 4) {
      int4 s = src4[e4];
      int4 d = dst4[e4];
      int p0 = atomicAdd(&cnt[d.x], 1); csr96[d.x * CAP + p0] = s.x;
      int p1 = atomicAdd(&cnt[d.y], 1); csr96[d.y * CAP + p1] = s.y;
      int p2 = atomicAdd(&cnt[d.z], 1); csr96[d.z * CAP + p2] = s.z;
      int p3 = atomicAdd(&cnt[d.w], 1); csr96[d.w * CAP + p3] = s.w;
    }
    return;
  }
  if (b == SCAT_BLOCKS) {
    // W1hp: 8 per-head B-frag tiles, B[k][n] with n=lane&15, k=(lane>>4)*8+j
    for (int idx = tid; idx < 8 * 512; idx += 256) {
      int tile = idx >> 9;
      int rem = idx & 511;
      int lane = rem >> 3, j = rem & 7;
      int k = (lane >> 4) * 8 + j;
      int n = lane & 15;
      W1hp[idx] = __float2half(W1[k * C1 + tile * 16 + n]);
    }
    // W2pp: 4 feat k-step tiles + 4 [Wl2|Wr2|0] k-step tiles
    for (int idx = tid; idx < 8 * 512; idx += 256) {
      int tile = idx >> 9;
      int rem = idx & 511;
      int lane = rem >> 3, j = rem & 7;
      int ks = tile & 3;
      int k = ks * 32 + (lane >> 4) * 8 + j;
      int n = lane & 15;
      float v = 0.f;
      if (tile < 4) {
        v = W2[k * OUT_F + n];
      } else if (n == 0) {
        float s = 0.f;
        for (int f = 0; f < 16; ++f) s += W2[k * OUT_F + f] * al2[f];
        v = s;
      } else if (n == 1) {
        float s = 0.f;
        for (int f = 0; f < 16; ++f) s += W2[k * OUT_F + f] * ar2[f];
        v = s;
      }
      W2pp[idx] = __float2half(v);
    }
    return;
  }
  // ---- xcast + el/er branch ----
  {
    __half* E = (__half*)ELERs;
    for (int idx = tid; idx < 512; idx += 256) {
      int lane = idx >> 3, j = idx & 7;
      int k = (lane >> 4) * 8 + j;
      int n = lane & 15;
      int hh_ = n & 7;
      const float* a = (n < 8) ? al1 : ar1;
      float s = 0.f;
      for (int f = 0; f < 16; ++f) s += W1[k * C1 + hh_ * 16 + f] * a[hh_ * 16 + f];
      E[idx] = __float2half(s);
    }
  }
  __syncthreads();
  int wave = tid >> 6, lane = tid & 63;
  int m = lane & 15, quad = lane >> 4;
  int rowbase = (b - SCAT_BLOCKS - 1) * 64 + wave * 16;
  int row = rowbase + m;
  const float4* xp = (const float4*)(x + row * IN_F + quad * 8);
  float4 a0 = xp[0], a1 = xp[1];
  h8 af;
  af[0] = (_Float16)a0.x; af[1] = (_Float16)a0.y;
  af[2] = (_Float16)a0.z; af[3] = (_Float16)a0.w;
  af[4] = (_Float16)a1.x; af[5] = (_Float16)a1.y;
  af[6] = (_Float16)a1.z; af[7] = (_Float16)a1.w;
  *(h8*)(xh + (size_t)row * IN_F + quad * 8) = af;   // fp16 x copy
  {
    h8 bf = ELERs[lane];
    f32x4 c = {0.f, 0.f, 0.f, 0.f};
    c = __builtin_amdgcn_mfma_f32_16x16x32_f16(af, bf, c, 0, 0, 0);
#pragma unroll
    for (int r = 0; r < 4; ++r) {
      int orow = rowbase + quad * 4 + r;
      if (m < 8) el1[orow * H1 + m] = c[r];
      else       er1[orow * H1 + (m - 8)] = c[r];
    }
  }
}

// ---------------------------------------------------------------------------
// K2: layer-1 x-form aggregate (pk_fma hot loop — LOCKED: six structural
// variants bracketed R11-R16, this is the floor) + FUSED mid GEMMs in a
// barrier-fenced epilogue. Each block's 4 waves hold one 16-row M-tile
// (4 nodes x 4 t): normalized aggx tile -> padded LDS; phase 1 (per-head
// GEMM, 2 heads/wave); phase 2 (feat2/el2/er2 GEMM, wave 0).
// ---------------------------------------------------------------------------
__global__ __launch_bounds__(256) void k_agg1m(
    const __half* __restrict__ xh,       // [nt][32]
    const float* __restrict__ el1,       // [n][32] = [n][t][8]
    const float* __restrict__ er1,
    const int* __restrict__ cnt, const int* __restrict__ csr96,
    const __half* __restrict__ W1hp, const float* __restrict__ b1,
    const __half* __restrict__ W2pp,
    __half* __restrict__ feat2h, float* __restrict__ el2,
    float* __restrict__ er2) {
  __shared__ __half axs[16][264];        // 8.4 KB aggx tile, stride-264 pad
  __shared__ __half hs[16][136];         // 4.3 KB h tile, stride-136 pad
  int tid = threadIdx.x;
  int wv = tid >> 6, lane = tid & 63;
  int n = blockIdx.x * 4 + wv;
  int slot = lane >> 1;                  // (t,h): t=slot>>3, h=slot&7
  int t = lane >> 4;                     // == slot>>3
  int hf = lane & 1;
  float er_i = er1[(size_t)n * 32 + slot];
  int deg = cnt[n];
  const int* eb = csr96 + (size_t)n * CAP;
  h8 accA = {0, 0, 0, 0, 0, 0, 0, 0};
  h8 accB = {0, 0, 0, 0, 0, 0, 0, 0};
  float l = 0.f;
  for (int chunk = 0; chunk < deg; chunk += 64) {
    int m = min(64, deg - chunk);
    int sv = (lane < m) ? eb[chunk + lane] : 0;
    int iters = (m + 3) >> 2;
    for (int g = 0; g < iters; ++g) {
      int j = g * 4;
      int s0 = __builtin_amdgcn_readlane(sv, j + 0);
      int s1 = __builtin_amdgcn_readlane(sv, j + 1);
      int s2 = __builtin_amdgcn_readlane(sv, j + 2);
      int s3 = __builtin_amdgcn_readlane(sv, j + 3);
      float ew0 = el1[(size_t)s0 * 32 + slot];
      float ew1 = el1[(size_t)s1 * 32 + slot];
      float ew2 = el1[(size_t)s2 * 32 + slot];
      float ew3 = el1[(size_t)s3 * 32 + slot];
      const __half* x0 = xh + (size_t)(s0 * 4 + t) * 32 + hf * 16;
      const __half* x1 = xh + (size_t)(s1 * 4 + t) * 32 + hf * 16;
      const __half* x2 = xh + (size_t)(s2 * 4 + t) * 32 + hf * 16;
      const __half* x3 = xh + (size_t)(s3 * 4 + t) * 32 + hf * 16;
      h8 a0 = *(const h8*)x0, b0 = *(const h8*)(x0 + 8);
      h8 a1 = *(const h8*)x1, b1_ = *(const h8*)(x1 + 8);
      h8 a2 = *(const h8*)x2, b2_ = *(const h8*)(x2 + 8);
      h8 a3 = *(const h8*)x3, b3_ = *(const h8*)(x3 + 8);
#define CONSUME(K, EW, XA, XB)                                    \
      {                                                           \
        float w_ = lrelu_exp(EW + er_i);                          \
        w_ = (j + K < m) ? w_ : 0.f;                              \
        l += w_;                                                  \
        _Float16 wh_ = (_Float16)w_;                              \
        h8 w8_ = {wh_, wh_, wh_, wh_, wh_, wh_, wh_, wh_};        \
        accA += w8_ * XA;                                         \
        accB += w8_ * XB;                                         \
      }
      CONSUME(0, ew0, a0, b0) CONSUME(1, ew1, a1, b1_)
      CONSUME(2, ew2, a2, b2_) CONSUME(3, ew3, a3, b3_)
#undef CONSUME
    }
  }
  float inv = (l > 0.f) ? (1.f / l) : 0.f;
  {
    h8 r0, r1;
#pragma unroll
    for (int q = 0; q < 8; ++q) {
      r0[q] = (_Float16)((float)accA[q] * inv);
      r1[q] = (_Float16)((float)accB[q] * inv);
    }
    int hh_ = slot & 7;
    __half* op = &axs[wv * 4 + t][hh_ * 32 + hf * 16];
    *(h8*)op = r0;
    *(h8*)(op + 8) = r1;
  }
  __syncthreads();

  // ---- fused mid epilogue (barrier-fenced, cold code) ----
  int m = lane & 15, quad = lane >> 4;
  const h8* bp1 = (const h8*)W1hp;
  // phase 1: wave wv computes heads 2wv, 2wv+1 -> hs
#pragma unroll
  for (int hi = 0; hi < 2; ++hi) {
    int head = wv * 2 + hi;
    h8 af = *(const h8*)&axs[m][head * 32 + quad * 8];
    f32x4 c = {0.f, 0.f, 0.f, 0.f};
    c = __builtin_amdgcn_mfma_f32_16x16x32_f16(af, bp1[head * 64 + lane], c, 0, 0, 0);
    float bv = b1[head * 16 + m];
#pragma unroll
    for (int r = 0; r < 4; ++r)
      hs[quad * 4 + r][head * 16 + m] = __float2half(c[r] + bv);
  }
  __syncthreads();
  if (wv != 0) return;
  // phase 2: wave 0 computes feat2 + el2/er2 for the 16-row tile
  const h8* bp2 = (const h8*)W2pp;
  f32x4 cF = {0.f, 0.f, 0.f, 0.f};
  f32x4 cE = {0.f, 0.f, 0.f, 0.f};
#pragma unroll
  for (int ks = 0; ks < 4; ++ks) {
    h8 af = *(const h8*)&hs[m][ks * 32 + quad * 8];
    cF = __builtin_amdgcn_mfma_f32_16x16x32_f16(af, bp2[ks * 64 + lane], cF, 0, 0, 0);
    cE = __builtin_amdgcn_mfma_f32_16x16x32_f16(af, bp2[(4 + ks) * 64 + lane], cE, 0, 0, 0);
  }
#pragma unroll
  for (int r = 0; r < 4; ++r) {
    int orow = blockIdx.x * 16 + quad * 4 + r;
    feat2h[(size_t)orow * OUT_F + m] = __float2half(cF[r]);
    if (m == 0) el2[orow] = cE[r];
    if (m == 1) er2[orow] = cE[r];
  }
}

// ---------------------------------------------------------------------------
// K3: layer-2 aggregate, no-routing form. One wave per node; lane owns
// (t = lane>>4, f = lane&15); alpha computed locally; 8-edge batches.
// ---------------------------------------------------------------------------
__global__ __launch_bounds__(256) void k_agg2x(
    const __half* __restrict__ feat2h,   // [nt][16]
    const float* __restrict__ el2, const float* __restrict__ er2,  // [nt]
    const int* __restrict__ cnt, const int* __restrict__ csr96,
    const float* __restrict__ b2, float* __restrict__ out) {
  int tid = threadIdx.x;
  int wv = tid >> 6, lane = tid & 63;
  int n = blockIdx.x * 4 + wv;
  int t = lane >> 4, f = lane & 15;
  float ern = er2[n * 4 + t];
  int deg = cnt[n];
  const int* eb = csr96 + (size_t)n * CAP;
  float acc = 0.f, l = 0.f;
  for (int chunk = 0; chunk < deg; chunk += 64) {
    int m = min(64, deg - chunk);
    int sv = (lane < m) ? eb[chunk + lane] : 0;
    int iters = (m + 7) >> 3;
    for (int g = 0; g < iters; ++g) {
      int j = g * 8;
      int s0 = __builtin_amdgcn_readlane(sv, j + 0);
      int s1 = __builtin_amdgcn_readlane(sv, j + 1);
      int s2 = __builtin_amdgcn_readlane(sv, j + 2);
      int s3 = __builtin_amdgcn_readlane(sv, j + 3);
      int s4 = __builtin_amdgcn_readlane(sv, j + 4);
      int s5 = __builtin_amdgcn_readlane(sv, j + 5);
      int s6 = __builtin_amdgcn_readlane(sv, j + 6);
      int s7 = __builtin_amdgcn_readlane(sv, j + 7);
      float e0 = el2[s0 * 4 + t];
      float e1 = el2[s1 * 4 + t];
      float e2 = el2[s2 * 4 + t];
      float e3 = el2[s3 * 4 + t];
      float e4 = el2[s4 * 4 + t];
      float e5 = el2[s5 * 4 + t];
      float e6 = el2[s6 * 4 + t];
      float e7 = el2[s7 * 4 + t];
      __half f0 = feat2h[(size_t)(s0 * 4 + t) * OUT_F + f];
      __half f1 = feat2h[(size_t)(s1 * 4 + t) * OUT_F + f];
      __half f2 = feat2h[(size_t)(s2 * 4 + t) * OUT_F + f];
      __half f3 = feat2h[(size_t)(s3 * 4 + t) * OUT_F + f];
      __half f4 = feat2h[(size_t)(s4 * 4 + t) * OUT_F + f];
      __half f5 = feat2h[(size_t)(s5 * 4 + t) * OUT_F + f];
      __half f6 = feat2h[(size_t)(s6 * 4 + t) * OUT_F + f];
      __half f7 = feat2h[(size_t)(s7 * 4 + t) * OUT_F + f];
#define CONSUME(K, EW, FV)                                        \
      {                                                           \
        float w_ = lrelu_exp(EW + ern);                           \
        w_ = (j + K < m) ? w_ : 0.f;                              \
        l += w_;                                                  \
        acc = fmaf(w_, __half2float(FV), acc);                    \
      }
      CONSUME(0, e0, f0) CONSUME(1, e1, f1)
      CONSUME(2, e2, f2) CONSUME(3, e3, f3)
      CONSUME(4, e4, f4) CONSUME(5, e5, f5)
      CONSUME(6, e6, f6) CONSUME(7, e7, f7)
#undef CONSUME
    }
  }
  float inv = (l > 0.f) ? (1.f / l) : 0.f;
  out[(size_t)(n * 4 + t) * OUT_F + f] = acc * inv + b2[f];
}

// ---------------------------------------------------------------------------
extern "C" void kernel_launch(void* const* d_in, const int* in_sizes, int n_in,
                              void* d_out, int out_size, void* d_ws, size_t ws_size,
                              hipStream_t stream) {
  const float* x   = (const float*)d_in[0];
  const int*   src = (const int*)d_in[1];
  const int*   dst = (const int*)d_in[2];
  const float* W1  = (const float*)d_in[3];
  const float* al1 = (const float*)d_in[4];
  const float* ar1 = (const float*)d_in[5];
  const float* b1  = (const float*)d_in[6];
  const float* W2  = (const float*)d_in[7];
  const float* al2 = (const float*)d_in[8];
  const float* ar2 = (const float*)d_in[9];
  const float* b2  = (const float*)d_in[10];
  float* out = (float*)d_out;

  // Workspace layout (bytes, 256-aligned chunks), ~22 MB total
  char* w = (char*)d_ws;
  __half* xh     = (__half*)w; w += (size_t)NT * IN_F * 2;      // 5.12 MB
  __half* feat2h = (__half*)w; w += (size_t)NT * OUT_F * 2;     // 2.56 MB
  float*  el1    = (float*)w;  w += (size_t)NT * H1 * 4;        // 2.56 MB
  float*  er1    = (float*)w;  w += (size_t)NT * H1 * 4;
  float*  el2    = (float*)w;  w += (size_t)NT * 4;             // 0.32 MB
  float*  er2    = (float*)w;  w += (size_t)NT * 4;
  __half* W1hp   = (__half*)w; w += (size_t)8 * 512 * 2;
  __half* W2pp   = (__half*)w; w += (size_t)8 * 512 * 2;
  int* cnt     = (int*)w;      w += (size_t)NN * 4;             // 80 KB
  int* csr96   = (int*)w;      w += (size_t)NN * CAP * 4;       // 7.68 MB

  hipMemsetAsync(cnt, 0, NN * sizeof(int), stream);

  k_front<<<SCAT_BLOCKS + 1 + XCAST_BLOCKS, 256, 0, stream>>>(
      x, W1, al1, ar1, W2, al2, ar2, (const int4*)src, (const int4*)dst,
      cnt, csr96, xh, el1, er1, W1hp, W2pp);
  k_agg1m<<<NN / 4, 256, 0, stream>>>(xh, el1, er1, cnt, csr96,
                                      W1hp, b1, W2pp, feat2h, el2, er2);
  k_agg2x<<<NN / 4, 256, 0, stream>>>(feat2h, el2, er2, cnt, csr96, b2, out);
}